// Round 8
// baseline (76.613 us; speedup 1.0000x reference)
//
#include <hip/hip_runtime.h>

#define D_CLAMP2 100.0f   // D_CLAMP^2 ; min(sqrt(x),10) == sqrt(min(x,100))
#define EPS_F    1e-4f
#define Z_F      10.0f
#define JCH      64       // j atoms per block
#define IPL      2        // frames per lane (packed into v_pk_fma_f32 halves)

typedef float v2f __attribute__((ext_vector_type(2)));

// ---------------------------------------------------------------------------
// LANE OWNS TWO FRAMES (i, i+256); their 2x21 constants live in 42 VGPRs as
// {frameA,frameB} v2f pairs so the two pair-computations share one
// v_pk_fma_f32 stream. The 64-atom j-slice is staged once into LDS; the hot
// loop reads 2x ds_read_b128 (wave-uniform broadcast) per jj and computes
// TWO pairs: 21 pk-FMA + 2 min + 2 sqrt + 2 add = ~13.5 issue-slots and
// 16 B LDS-return per pair. Partials to d_ws; tiny reduce kernel writes out.
// ---------------------------------------------------------------------------
__global__ __launch_bounds__(256) void fape_main(
    const float* __restrict__ pred_rot,   // [B,N,3,3]
    const float* __restrict__ pred_trans, // [B,N,3]
    const float* __restrict__ pred_pos,   // [B,N,3]
    const float* __restrict__ true_rot,   // [B,N,3,3]
    const float* __restrict__ true_trans, // [B,N,3]
    const float* __restrict__ true_pos,   // [B,N,3]
    float* __restrict__ partial,          // [B, gridDim.x]
    int N, int jChunks)
{
    const int jc  = blockIdx.x % jChunks;   // 64-wide j slice
    const int fcb = blockIdx.x / jChunks;   // 512-frame i slice
    const int b   = blockIdx.y;
    const int j0  = jc * JCH;

    // ---- Stage j-slice into LDS: row jj = {a0,a1,a2,b0 | b1,b2,pad,pad} ----
    __shared__ float4 sy[JCH * 2];
    {
        float* syf = (float*)sy;
        const float* XPb = pred_pos + (size_t)b * N * 3;
        const float* XTb = true_pos + (size_t)b * N * 3;
        for (int idx = threadIdx.x; idx < JCH * 6; idx += 256) {
            const int jj = idx / 6, c = idx - 6 * jj;
            const int jA = j0 + jj;
            const int jv = jA < N ? jA : N - 1;
            syf[jj * 8 + c] = (c < 3) ? XPb[3 * jv + c] : XTb[3 * jv + c - 3];
        }
    }

    // ---- Two frames per lane: constants packed {A,B} into v2f ----
    const int iBase = fcb * (256 * IPL) + threadIdx.x;
    v2f CRP[9], CRN[9], CCN[3];             // CRP[o*3+q] = {rpA[3q+o], rpB[3q+o]}
    float wFv[IPL];
#pragma unroll
    for (int f = 0; f < IPL; ++f) {
        const int ii = iBase + f * 256;
        wFv[f] = (ii < N) ? 1.0f : 0.0f;
        const int iv = ii < N ? ii : N - 1;
        const size_t fi = (size_t)b * N + iv;
        const float* Rp = pred_rot + fi * 9;
        const float* Rt = true_rot + fi * 9;
        float rp[9], rt[9];
#pragma unroll
        for (int q = 0; q < 9; ++q) { rp[q] = Rp[q]; rt[q] = Rt[q]; }
        const float* tpv = pred_trans + fi * 3;
        const float* ttv = true_trans + fi * 3;
        const float tp0 = tpv[0], tp1 = tpv[1], tp2 = tpv[2];
        const float tt0 = ttv[0], tt1 = ttv[1], tt2 = ttv[2];
#pragma unroll
        for (int o = 0; o < 3; ++o) {
            const float cno = (rt[0+o]*tt0 + rt[3+o]*tt1 + rt[6+o]*tt2)
                            - (rp[0+o]*tp0 + rp[3+o]*tp1 + rp[6+o]*tp2);
            if (f == 0) CCN[o].x = cno; else CCN[o].y = cno;
#pragma unroll
            for (int q = 0; q < 3; ++q) {
                if (f == 0) { CRP[o*3+q].x = rp[3*q+o]; CRN[o*3+q].x = -rt[3*q+o]; }
                else        { CRP[o*3+q].y = rp[3*q+o]; CRN[o*3+q].y = -rt[3*q+o]; }
            }
        }
    }
    const v2f EPS2 = {EPS_F, EPS_F};

    __syncthreads();

    float sumA = 0.0f, sumB = 0.0f;
    if (j0 + JCH <= N) {
        // Full chunk: no tail clamps in the hot loop.
#pragma unroll 4
        for (int jj = 0; jj < JCH; ++jj) {
            const float4 ya = sy[2*jj + 0];     // ds_read_b128, uniform addr
            const float4 yb = sy[2*jj + 1];
            const v2f A0 = {ya.x, ya.x}, A1 = {ya.y, ya.y}, A2 = {ya.z, ya.z};
            const v2f B0 = {ya.w, ya.w}, B1 = {yb.x, yb.x}, B2 = {yb.y, yb.y};
            const v2f D0 = __builtin_elementwise_fma(CRP[0], A0,
                           __builtin_elementwise_fma(CRP[1], A1,
                           __builtin_elementwise_fma(CRP[2], A2,
                           __builtin_elementwise_fma(CRN[0], B0,
                           __builtin_elementwise_fma(CRN[1], B1,
                           __builtin_elementwise_fma(CRN[2], B2, CCN[0]))))));
            const v2f D1 = __builtin_elementwise_fma(CRP[3], A0,
                           __builtin_elementwise_fma(CRP[4], A1,
                           __builtin_elementwise_fma(CRP[5], A2,
                           __builtin_elementwise_fma(CRN[3], B0,
                           __builtin_elementwise_fma(CRN[4], B1,
                           __builtin_elementwise_fma(CRN[5], B2, CCN[1]))))));
            const v2f D2 = __builtin_elementwise_fma(CRP[6], A0,
                           __builtin_elementwise_fma(CRP[7], A1,
                           __builtin_elementwise_fma(CRP[8], A2,
                           __builtin_elementwise_fma(CRN[6], B0,
                           __builtin_elementwise_fma(CRN[7], B1,
                           __builtin_elementwise_fma(CRN[8], B2, CCN[2]))))));
            const v2f S2 = __builtin_elementwise_fma(D0, D0,
                           __builtin_elementwise_fma(D1, D1,
                           __builtin_elementwise_fma(D2, D2, EPS2)));
            sumA += __builtin_amdgcn_sqrtf(fminf(S2.x, D_CLAMP2));
            sumB += __builtin_amdgcn_sqrtf(fminf(S2.y, D_CLAMP2));
        }
    } else {
        // Tail chunk (not hit when N % JCH == 0): weighted accumulate.
#pragma unroll 4
        for (int jj = 0; jj < JCH; ++jj) {
            const float wj = (j0 + jj < N) ? 1.0f : 0.0f;
            const float4 ya = sy[2*jj + 0];
            const float4 yb = sy[2*jj + 1];
            const v2f A0 = {ya.x, ya.x}, A1 = {ya.y, ya.y}, A2 = {ya.z, ya.z};
            const v2f B0 = {ya.w, ya.w}, B1 = {yb.x, yb.x}, B2 = {yb.y, yb.y};
            const v2f D0 = __builtin_elementwise_fma(CRP[0], A0,
                           __builtin_elementwise_fma(CRP[1], A1,
                           __builtin_elementwise_fma(CRP[2], A2,
                           __builtin_elementwise_fma(CRN[0], B0,
                           __builtin_elementwise_fma(CRN[1], B1,
                           __builtin_elementwise_fma(CRN[2], B2, CCN[0]))))));
            const v2f D1 = __builtin_elementwise_fma(CRP[3], A0,
                           __builtin_elementwise_fma(CRP[4], A1,
                           __builtin_elementwise_fma(CRP[5], A2,
                           __builtin_elementwise_fma(CRN[3], B0,
                           __builtin_elementwise_fma(CRN[4], B1,
                           __builtin_elementwise_fma(CRN[5], B2, CCN[1]))))));
            const v2f D2 = __builtin_elementwise_fma(CRP[6], A0,
                           __builtin_elementwise_fma(CRP[7], A1,
                           __builtin_elementwise_fma(CRP[8], A2,
                           __builtin_elementwise_fma(CRN[6], B0,
                           __builtin_elementwise_fma(CRN[7], B1,
                           __builtin_elementwise_fma(CRN[8], B2, CCN[2]))))));
            const v2f S2 = __builtin_elementwise_fma(D0, D0,
                           __builtin_elementwise_fma(D1, D1,
                           __builtin_elementwise_fma(D2, D2, EPS2)));
            sumA = fmaf(wj, __builtin_amdgcn_sqrtf(fminf(S2.x, D_CLAMP2)), sumA);
            sumB = fmaf(wj, __builtin_amdgcn_sqrtf(fminf(S2.y, D_CLAMP2)), sumB);
        }
    }
    float sum = sumA * wFv[0] + sumB * wFv[1];

    // Block reduction -> one plain store (no atomics).
#pragma unroll
    for (int off = 32; off > 0; off >>= 1)
        sum += __shfl_down(sum, off, 64);

    __shared__ float smem[4];
    const int lane = threadIdx.x & 63;
    const int wave = threadIdx.x >> 6;
    if (lane == 0) smem[wave] = sum;
    __syncthreads();
    if (threadIdx.x == 0)
        partial[(size_t)b * gridDim.x + blockIdx.x] = smem[0] + smem[1] + smem[2] + smem[3];
}

// One block per batch: deterministic tree-reduce of the partials, write out.
__global__ __launch_bounds__(256) void fape_reduce(
    const float* __restrict__ partial, float* __restrict__ out, int nPart, int N)
{
    const int b = blockIdx.x;
    float s = 0.0f;
    for (int t = threadIdx.x; t < nPart; t += 256)
        s += partial[(size_t)b * nPart + t];
#pragma unroll
    for (int off = 32; off > 0; off >>= 1)
        s += __shfl_down(s, off, 64);
    __shared__ float smem[4];
    const int lane = threadIdx.x & 63;
    const int wave = threadIdx.x >> 6;
    if (lane == 0) smem[wave] = s;
    __syncthreads();
    if (threadIdx.x == 0) {
        const float tot = smem[0] + smem[1] + smem[2] + smem[3];
        out[b] = tot / (Z_F * (float)N * (float)N);
    }
}

extern "C" void kernel_launch(void* const* d_in, const int* in_sizes, int n_in,
                              void* d_out, int out_size, void* d_ws, size_t ws_size,
                              hipStream_t stream) {
    const float* pred_rot   = (const float*)d_in[0];
    const float* pred_trans = (const float*)d_in[1];
    const float* pred_pos   = (const float*)d_in[2];
    const float* true_rot   = (const float*)d_in[3];
    const float* true_trans = (const float*)d_in[4];
    const float* true_pos   = (const float*)d_in[5];
    float* out = (float*)d_out;

    const int B = out_size;                  // 4
    const int BN = in_sizes[1] / 3;          // B*N
    const int N = BN / B;                    // 2048

    const int jChunks = (N + JCH - 1) / JCH;             // 32
    const int iChunks = (N + 256 * IPL - 1) / (256 * IPL); // 4
    const int nPart   = iChunks * jChunks;               // 128

    float* partial = (float*)d_ws;           // B*nPart*4 = 2 KB

    dim3 grid(nPart, B);                     // (128, 4) = 512 blocks
    fape_main<<<grid, 256, 0, stream>>>(pred_rot, pred_trans, pred_pos,
                                        true_rot, true_trans, true_pos,
                                        partial, N, jChunks);
    fape_reduce<<<B, 256, 0, stream>>>(partial, out, nPart, N);
}

// Round 9
// 76.590 us; speedup vs baseline: 1.0003x; 1.0003x over previous
//
#include <hip/hip_runtime.h>

#define D_CLAMP2 100.0f   // D_CLAMP^2 ; min(sqrt(x),10) == sqrt(min(x,100))
#define EPS_F    1e-4f
#define Z_F      10.0f
#define JCH      64       // j atoms per block
#define IPL      2        // frames per lane (packed into v_pk_fma_f32 halves)

typedef float v2f __attribute__((ext_vector_type(2)));

// ---------------------------------------------------------------------------
// Pass 0: per-frame constants, computed ONCE and stored SoA-transposed:
//   plane p in [0,21), cons[p*BN + f]:
//     p = o*3+q      : rp[3q+o]          (Rp^T laid out for output comp o)
//     p = 9 + o*3+q  : -rt[3q+o]
//     p = 18 + o     : cn[o] = Rt^T tt - Rp^T tp
// Reads are scattered (once per frame total); writes are coalesced.
// Main kernel then loads constants with fully-coalesced stride-1 loads.
// ---------------------------------------------------------------------------
__global__ __launch_bounds__(256) void fape_pre(
    const float* __restrict__ pred_rot, const float* __restrict__ pred_trans,
    const float* __restrict__ true_rot, const float* __restrict__ true_trans,
    float* __restrict__ cons, int BN)
{
    const int f = blockIdx.x * 256 + threadIdx.x;
    if (f >= BN) return;
    float rp[9], rt[9];
    const float* Rp = pred_rot + (size_t)f * 9;
    const float* Rt = true_rot + (size_t)f * 9;
#pragma unroll
    for (int q = 0; q < 9; ++q) { rp[q] = Rp[q]; rt[q] = Rt[q]; }
    const float* tpv = pred_trans + (size_t)f * 3;
    const float* ttv = true_trans + (size_t)f * 3;
    const float tp0 = tpv[0], tp1 = tpv[1], tp2 = tpv[2];
    const float tt0 = ttv[0], tt1 = ttv[1], tt2 = ttv[2];
#pragma unroll
    for (int o = 0; o < 3; ++o) {
#pragma unroll
        for (int q = 0; q < 3; ++q) {
            cons[(size_t)(o*3+q) * BN + f]     =  rp[3*q+o];
            cons[(size_t)(9+o*3+q) * BN + f]   = -rt[3*q+o];
        }
        cons[(size_t)(18+o) * BN + f] =
              (rt[0+o]*tt0 + rt[3+o]*tt1 + rt[6+o]*tt2)
            - (rp[0+o]*tp0 + rp[3+o]*tp1 + rp[6+o]*tp2);
    }
}

// ---------------------------------------------------------------------------
// Main: lane owns TWO frames (i, i+256); constants arrive via 42 coalesced
// dword loads from the SoA planes. 64-atom j-slice staged in LDS; hot loop =
// 2x ds_read_b128 broadcast + 21 pk-FMA + 2 min/sqrt/add per jj (2 pairs).
// Partials to d_ws; reduce kernel writes out (no atomics, no memset).
// ---------------------------------------------------------------------------
__global__ __launch_bounds__(256) void fape_main(
    const float* __restrict__ cons,       // [21, BN] SoA
    const float* __restrict__ pred_pos,   // [B,N,3]
    const float* __restrict__ true_pos,   // [B,N,3]
    float* __restrict__ partial,          // [B, gridDim.x]
    int N, int BN, int jChunks)
{
    const int jc  = blockIdx.x % jChunks;   // 64-wide j slice
    const int fcb = blockIdx.x / jChunks;   // 512-frame i slice
    const int b   = blockIdx.y;
    const int j0  = jc * JCH;

    // ---- Stage j-slice into LDS: row jj = {a0,a1,a2,b0 | b1,b2,pad,pad} ----
    __shared__ float4 sy[JCH * 2];
    {
        float* syf = (float*)sy;
        const float* XPb = pred_pos + (size_t)b * N * 3;
        const float* XTb = true_pos + (size_t)b * N * 3;
        for (int idx = threadIdx.x; idx < JCH * 6; idx += 256) {
            const int jj = idx / 6, c = idx - 6 * jj;
            const int jA = j0 + jj;
            const int jv = jA < N ? jA : N - 1;
            syf[jj * 8 + c] = (c < 3) ? XPb[3 * jv + c] : XTb[3 * jv + c - 3];
        }
    }

    // ---- Coalesced SoA constant loads for the lane's two frames ----
    const int iA = fcb * (256 * IPL) + threadIdx.x;
    const int iB = iA + 256;
    const float wA = (iA < N) ? 1.0f : 0.0f;
    const float wB = (iB < N) ? 1.0f : 0.0f;
    const size_t fA = (size_t)b * N + (iA < N ? iA : N - 1);
    const size_t fB = (size_t)b * N + (iB < N ? iB : N - 1);

    v2f CRP[9], CRN[9], CCN[3];
#pragma unroll
    for (int p = 0; p < 9; ++p) {
        CRP[p].x = cons[(size_t)p * BN + fA];
        CRP[p].y = cons[(size_t)p * BN + fB];
        CRN[p].x = cons[(size_t)(9+p) * BN + fA];
        CRN[p].y = cons[(size_t)(9+p) * BN + fB];
    }
#pragma unroll
    for (int o = 0; o < 3; ++o) {
        CCN[o].x = cons[(size_t)(18+o) * BN + fA];
        CCN[o].y = cons[(size_t)(18+o) * BN + fB];
    }
    const v2f EPS2 = {EPS_F, EPS_F};

    __syncthreads();

    float sumA = 0.0f, sumB = 0.0f;
    if (j0 + JCH <= N) {
#pragma unroll 4
        for (int jj = 0; jj < JCH; ++jj) {
            const float4 ya = sy[2*jj + 0];     // ds_read_b128, uniform addr
            const float4 yb = sy[2*jj + 1];
            const v2f A0 = {ya.x, ya.x}, A1 = {ya.y, ya.y}, A2 = {ya.z, ya.z};
            const v2f B0 = {ya.w, ya.w}, B1 = {yb.x, yb.x}, B2 = {yb.y, yb.y};
            const v2f D0 = __builtin_elementwise_fma(CRP[0], A0,
                           __builtin_elementwise_fma(CRP[1], A1,
                           __builtin_elementwise_fma(CRP[2], A2,
                           __builtin_elementwise_fma(CRN[0], B0,
                           __builtin_elementwise_fma(CRN[1], B1,
                           __builtin_elementwise_fma(CRN[2], B2, CCN[0]))))));
            const v2f D1 = __builtin_elementwise_fma(CRP[3], A0,
                           __builtin_elementwise_fma(CRP[4], A1,
                           __builtin_elementwise_fma(CRP[5], A2,
                           __builtin_elementwise_fma(CRN[3], B0,
                           __builtin_elementwise_fma(CRN[4], B1,
                           __builtin_elementwise_fma(CRN[5], B2, CCN[1]))))));
            const v2f D2 = __builtin_elementwise_fma(CRP[6], A0,
                           __builtin_elementwise_fma(CRP[7], A1,
                           __builtin_elementwise_fma(CRP[8], A2,
                           __builtin_elementwise_fma(CRN[6], B0,
                           __builtin_elementwise_fma(CRN[7], B1,
                           __builtin_elementwise_fma(CRN[8], B2, CCN[2]))))));
            const v2f S2 = __builtin_elementwise_fma(D0, D0,
                           __builtin_elementwise_fma(D1, D1,
                           __builtin_elementwise_fma(D2, D2, EPS2)));
            sumA += __builtin_amdgcn_sqrtf(fminf(S2.x, D_CLAMP2));
            sumB += __builtin_amdgcn_sqrtf(fminf(S2.y, D_CLAMP2));
        }
    } else {
#pragma unroll 4
        for (int jj = 0; jj < JCH; ++jj) {
            const float wj = (j0 + jj < N) ? 1.0f : 0.0f;
            const float4 ya = sy[2*jj + 0];
            const float4 yb = sy[2*jj + 1];
            const v2f A0 = {ya.x, ya.x}, A1 = {ya.y, ya.y}, A2 = {ya.z, ya.z};
            const v2f B0 = {ya.w, ya.w}, B1 = {yb.x, yb.x}, B2 = {yb.y, yb.y};
            const v2f D0 = __builtin_elementwise_fma(CRP[0], A0,
                           __builtin_elementwise_fma(CRP[1], A1,
                           __builtin_elementwise_fma(CRP[2], A2,
                           __builtin_elementwise_fma(CRN[0], B0,
                           __builtin_elementwise_fma(CRN[1], B1,
                           __builtin_elementwise_fma(CRN[2], B2, CCN[0]))))));
            const v2f D1 = __builtin_elementwise_fma(CRP[3], A0,
                           __builtin_elementwise_fma(CRP[4], A1,
                           __builtin_elementwise_fma(CRP[5], A2,
                           __builtin_elementwise_fma(CRN[3], B0,
                           __builtin_elementwise_fma(CRN[4], B1,
                           __builtin_elementwise_fma(CRN[5], B2, CCN[1]))))));
            const v2f D2 = __builtin_elementwise_fma(CRP[6], A0,
                           __builtin_elementwise_fma(CRP[7], A1,
                           __builtin_elementwise_fma(CRP[8], A2,
                           __builtin_elementwise_fma(CRN[6], B0,
                           __builtin_elementwise_fma(CRN[7], B1,
                           __builtin_elementwise_fma(CRN[8], B2, CCN[2]))))));
            const v2f S2 = __builtin_elementwise_fma(D0, D0,
                           __builtin_elementwise_fma(D1, D1,
                           __builtin_elementwise_fma(D2, D2, EPS2)));
            sumA = fmaf(wj, __builtin_amdgcn_sqrtf(fminf(S2.x, D_CLAMP2)), sumA);
            sumB = fmaf(wj, __builtin_amdgcn_sqrtf(fminf(S2.y, D_CLAMP2)), sumB);
        }
    }
    float sum = sumA * wA + sumB * wB;

    // Block reduction -> one plain store (no atomics).
#pragma unroll
    for (int off = 32; off > 0; off >>= 1)
        sum += __shfl_down(sum, off, 64);

    __shared__ float smem[4];
    const int lane = threadIdx.x & 63;
    const int wave = threadIdx.x >> 6;
    if (lane == 0) smem[wave] = sum;
    __syncthreads();
    if (threadIdx.x == 0)
        partial[(size_t)b * gridDim.x + blockIdx.x] = smem[0] + smem[1] + smem[2] + smem[3];
}

// One block per batch: deterministic tree-reduce of the partials, write out.
__global__ __launch_bounds__(256) void fape_reduce(
    const float* __restrict__ partial, float* __restrict__ out, int nPart, int N)
{
    const int b = blockIdx.x;
    float s = 0.0f;
    for (int t = threadIdx.x; t < nPart; t += 256)
        s += partial[(size_t)b * nPart + t];
#pragma unroll
    for (int off = 32; off > 0; off >>= 1)
        s += __shfl_down(s, off, 64);
    __shared__ float smem[4];
    const int lane = threadIdx.x & 63;
    const int wave = threadIdx.x >> 6;
    if (lane == 0) smem[wave] = s;
    __syncthreads();
    if (threadIdx.x == 0) {
        const float tot = smem[0] + smem[1] + smem[2] + smem[3];
        out[b] = tot / (Z_F * (float)N * (float)N);
    }
}

extern "C" void kernel_launch(void* const* d_in, const int* in_sizes, int n_in,
                              void* d_out, int out_size, void* d_ws, size_t ws_size,
                              hipStream_t stream) {
    const float* pred_rot   = (const float*)d_in[0];
    const float* pred_trans = (const float*)d_in[1];
    const float* pred_pos   = (const float*)d_in[2];
    const float* true_rot   = (const float*)d_in[3];
    const float* true_trans = (const float*)d_in[4];
    const float* true_pos   = (const float*)d_in[5];
    float* out = (float*)d_out;

    const int B = out_size;                  // 4
    const int BN = in_sizes[1] / 3;          // B*N
    const int N = BN / B;                    // 2048

    float* cons    = (float*)d_ws;           // 21*BN floats = 688 KB
    float* partial = cons + (size_t)21 * BN; // + B*nPart floats

    const int jChunks = (N + JCH - 1) / JCH;               // 32
    const int iChunks = (N + 256 * IPL - 1) / (256 * IPL); // 4
    const int nPart   = iChunks * jChunks;                 // 128

    fape_pre<<<(BN + 255) / 256, 256, 0, stream>>>(pred_rot, pred_trans,
                                                   true_rot, true_trans,
                                                   cons, BN);
    dim3 grid(nPart, B);                     // (128, 4) = 512 blocks
    fape_main<<<grid, 256, 0, stream>>>(cons, pred_pos, true_pos,
                                        partial, N, BN, jChunks);
    fape_reduce<<<B, 256, 0, stream>>>(partial, out, nPart, N);
}